// Round 7
// baseline (120.771 us; speedup 1.0000x reference)
//
#include <hip/hip_runtime.h>

#define NPTS 16384
#define NB   8
#define NM   2048
#define NC   128
#define EPSF 1e-8f

#define TQ   16                     // threads per query
#define QPB  16                     // queries per 256-thread block
#define GX   160                    // blocks per batch: 2560 slots >> segN(~2100) -> no tail

#define FEATST_BYTES ((size_t)NB * NM * NC * sizeof(float))   // 8 MB

// u64 key = (float_bits(d) << 32) | j : for d >= 0, u64 '<' == lexicographic (d, idx) '<'.
// Branchless: wave-any-update prob ~1 (R5 lesson) -> guard only adds exec-mask churn.
#define MERGE_KEY(e) do {                               \
    const bool _b2 = (e) < K2;                          \
    const bool _b1 = (e) < K1;                          \
    const bool _b0 = (e) < K0;                          \
    K2 = _b1 ? K1 : (_b2 ? (e) : K2);                   \
    K1 = _b0 ? K0 : (_b1 ? (e) : K1);                   \
    K0 = _b0 ? (e) : K0;                                \
} while (0)

// (B, C, M) -> (B, M, C) tiled transpose (verified R1-R3), +1 pad kills bank conflicts
__global__ __launch_bounds__(256) void transpose_feats(const float* __restrict__ in,
                                                       float* __restrict__ out) {
    __shared__ float tile[32][33];
    const int b  = blockIdx.z;
    const int j0 = blockIdx.x * 32;   // M dim
    const int c0 = blockIdx.y * 32;   // C dim
    const int tx = threadIdx.x;       // 32
    const int ty = threadIdx.y;       // 8
#pragma unroll
    for (int i = ty; i < 32; i += 8)
        tile[i][tx] = in[(size_t)b * NC * NM + (size_t)(c0 + i) * NM + (j0 + tx)];
    __syncthreads();
#pragma unroll
    for (int i = ty; i < 32; i += 8)
        out[(size_t)b * NM * NC + (size_t)(j0 + i) * NC + (c0 + tx)] = tile[tx][i];
}

// Block (batch b, window x): scan binds -> ranks; early-exit empty; stage batch b's points
// in LDS as float4 (one ds_read_b128/iter); 3-NN u64-keys TQ=16; gather featsT (or raw).
__global__ __launch_bounds__(256, 4) void fused(const float* __restrict__ unknown,
                                                const float* __restrict__ known,
                                                const int*   __restrict__ binds,
                                                const float* __restrict__ feats,
                                                const float* __restrict__ featsT,
                                                float* __restrict__ out,
                                                int useT) {
    __shared__ float4 kpt[NM];      // 32 KB, w unused
    __shared__ int qlist[QPB];
    __shared__ int wsum[4];

    const int tid  = threadIdx.x;
    const int b    = blockIdx.y;
    const int x    = blockIdx.x;
    const int lane = tid & 63;
    const int wave = tid >> 6;

    // ---- scan binds: per-thread count of batch-b points, 256-thread exclusive prefix ----
    const int4* b4 = (const int4*)binds;   // thread t owns binds[t*64 .. t*64+63]
    int myCnt = 0;
#pragma unroll
    for (int r = 0; r < 16; ++r) {
        const int4 v = b4[tid * 16 + r];
        myCnt += (v.x == b) + (v.y == b) + (v.z == b) + (v.w == b);
    }
    int inc = myCnt;
#pragma unroll
    for (int off = 1; off <= 32; off <<= 1) {
        const int n = __shfl_up(inc, off);
        if (lane >= off) inc += n;
    }
    if (lane == 63) wsum[wave] = inc;
    __syncthreads();
    int wbase = 0;
    for (int w = 0; w < wave; ++w) wbase += wsum[w];
    const int exPre = wbase + inc - myCnt;
    const int segN  = wsum[0] + wsum[1] + wsum[2] + wsum[3];

    if (x * QPB >= segN) return;           // block-uniform early exit

    // ---- stage known points of batch b into LDS (float4: single b128 read in hot loop) ----
    {
        const float* kb = known + (size_t)b * NM * 3;
        for (int j = tid; j < NM; j += 256) {
            float4 kp;
            kp.x = kb[j * 3 + 0];
            kp.y = kb[j * 3 + 1];
            kp.z = kb[j * 3 + 2];
            kp.w = 0.0f;
            kpt[j] = kp;
        }
    }

    const int qi = tid >> 4;   // query within block, 0..15
    const int t  = tid & 15;   // thread within query group

    // ---- window loop (executes once since GX*QPB >= segN; mop-up kept as safety net) ----
    for (int w0 = x * QPB; w0 < segN; w0 += GX * QPB) {
        __syncthreads();       // staging complete / previous window's qlist reads done
        if (exPre < w0 + QPB && exPre + myCnt > w0) {
            int rank = exPre;
#pragma unroll
            for (int r = 0; r < 16; ++r) {
                const int4 v = b4[tid * 16 + r];
                const int base = tid * 64 + r * 4;
                if (v.x == b) { if (rank >= w0 && rank < w0 + QPB) qlist[rank - w0] = base + 0; ++rank; }
                if (v.y == b) { if (rank >= w0 && rank < w0 + QPB) qlist[rank - w0] = base + 1; ++rank; }
                if (v.z == b) { if (rank >= w0 && rank < w0 + QPB) qlist[rank - w0] = base + 2; ++rank; }
                if (v.w == b) { if (rank >= w0 && rank < w0 + QPB) qlist[rank - w0] = base + 3; ++rank; }
            }
        }
        __syncthreads();

        const int valid = (segN - w0 < QPB) ? (segN - w0) : QPB;
        const int kq    = (qi < valid) ? qi : 0;   // duplicate query -> identical bytes, benign
        const int p     = qlist[kq];
        const float ux = unknown[p * 3 + 0];
        const float uy = unknown[p * 3 + 1];
        const float uz = unknown[p * 3 + 2];

        unsigned long long K0 = ~0ull, K1 = ~0ull, K2 = ~0ull;

#pragma unroll 8
        for (int i = 0; i < NM / TQ; ++i) {
            const int j = (i << 4) | t;
            const float4 kp = kpt[j];
            // strict rn, numpy association ((dx2+dy2)+dz2): selection bit-identical to ref
            const float dx = __fsub_rn(ux, kp.x);
            const float dy = __fsub_rn(uy, kp.y);
            const float dz = __fsub_rn(uz, kp.z);
            const float d  = __fadd_rn(__fadd_rn(__fmul_rn(dx, dx), __fmul_rn(dy, dy)),
                                       __fmul_rn(dz, dz));
            const unsigned long long key =
                ((unsigned long long)__float_as_uint(d) << 32) | (unsigned)j;
            MERGE_KEY(key);
        }

        // merge 16 partial top-3 lists (shfl_down tree; valid at group lane 0), broadcast
#pragma unroll
        for (int off = 8; off >= 1; off >>= 1) {
            const unsigned long long e0 = __shfl_down(K0, off);
            const unsigned long long e1 = __shfl_down(K1, off);
            const unsigned long long e2 = __shfl_down(K2, off);
            MERGE_KEY(e0);
            MERGE_KEY(e1);
            MERGE_KEY(e2);
        }
        const int src = lane & ~15;
        K0 = __shfl(K0, src); K1 = __shfl(K1, src); K2 = __shfl(K2, src);

        const float d0 = __uint_as_float((unsigned)(K0 >> 32));
        const float d1 = __uint_as_float((unsigned)(K1 >> 32));
        const float d2 = __uint_as_float((unsigned)(K2 >> 32));
        const int   i0 = (int)(unsigned)K0;
        const int   i1 = (int)(unsigned)K1;
        const int   i2 = (int)(unsigned)K2;

        const float t0 = 1.0f / (sqrtf(d0) + EPSF);
        const float t1 = 1.0f / (sqrtf(d1) + EPSF);
        const float t2 = 1.0f / (sqrtf(d2) + EPSF);
        const float s  = t0 + t1 + t2;
        const float w0w = t0 / s, w1w = t1 / s, w2w = t2 / s;

        if (useT) {
            // contiguous float4 rows: 3*512 B per query instead of 3*128 cache lines
            const float4* ftb = (const float4*)(featsT + (size_t)b * NM * NC);
            const float4* f0 = ftb + (size_t)i0 * (NC / 4);
            const float4* f1 = ftb + (size_t)i1 * (NC / 4);
            const float4* f2 = ftb + (size_t)i2 * (NC / 4);
            float4* o4 = (float4*)(out + (size_t)p * NC);
#pragma unroll
            for (int k = 0; k < 2; ++k) {
                const int c4 = t + k * 16;     // 16 lanes cover one 256B run
                const float4 a = f0[c4], bb = f1[c4], cc = f2[c4];
                float4 r;
                r.x = w0w * a.x + w1w * bb.x + w2w * cc.x;
                r.y = w0w * a.y + w1w * bb.y + w2w * cc.y;
                r.z = w0w * a.z + w1w * bb.z + w2w * cc.z;
                r.w = w0w * a.w + w1w * bb.w + w2w * cc.w;
                o4[c4] = r;
            }
        } else {
            const float* fb = feats + (size_t)b * NC * NM;
#pragma unroll
            for (int k = 0; k < 8; ++k) {
                const int c = t + (k << 4);
                const float* fc = fb + (size_t)c * NM;
                out[(size_t)p * NC + c] = w0w * fc[i0] + w1w * fc[i1] + w2w * fc[i2];
            }
        }
    }
}

extern "C" void kernel_launch(void* const* d_in, const int* in_sizes, int n_in,
                              void* d_out, int out_size, void* d_ws, size_t ws_size,
                              hipStream_t stream) {
    const float* unknown = (const float*)d_in[0];   // (n, 3)
    const float* known   = (const float*)d_in[1];   // (B, m, 3)
    const int*   binds   = (const int*)d_in[2];     // (n,)
    const float* feats   = (const float*)d_in[3];   // (B, C, m)
    float*       out     = (float*)d_out;           // (n, C, 1)

    const int useT = (ws_size >= FEATST_BYTES) ? 1 : 0;
    float* featsT = (float*)d_ws;

    if (useT) {
        dim3 tb(32, 8, 1);
        dim3 tg(NM / 32, NC / 32, NB);
        transpose_feats<<<tg, tb, 0, stream>>>(feats, featsT);
    }
    fused<<<dim3(GX, NB), 256, 0, stream>>>(unknown, known, binds, feats, featsT, out, useT);
}